// Round 1
// baseline (212.060 us; speedup 1.0000x reference)
//
#include <hip/hip_runtime.h>
#include <hip/hip_bf16.h>

#define BATCH 4
#define SEQ 4096
#define DMODEL 2048
#define HD 128
#define BS (BATCH*SEQ)

typedef __attribute__((ext_vector_type(8))) short short8;
typedef __attribute__((ext_vector_type(4))) float f32x4;
typedef __attribute__((ext_vector_type(4))) float float4v;
typedef unsigned short u16;
typedef unsigned int u32;

#define LOG2E 1.4426950408889634f
#define SCALE 0.08838834764831845f /* 1/sqrt(128) */

__device__ __forceinline__ u16 f2bf(float f){
  u32 u = __builtin_bit_cast(u32, f);
  u32 r = (u + 0x7FFFu + ((u >> 16) & 1u)) >> 16;
  return (u16)r;
}

__device__ __forceinline__ void gload16(const void* gptr, void* lptr){
  __builtin_amdgcn_global_load_lds((const __attribute__((address_space(1))) void*)gptr,
                                   (__attribute__((address_space(3))) void*)lptr, 16, 0, 0);
}

// ---------------- trig table: tab[s*64+j] = (cos, sin)(s * 10000^(-j/64)) ----------------
__global__ __launch_bounds__(256) void k_tab(float2* __restrict__ tab){
  int i = blockIdx.x*256 + threadIdx.x;      // 4096*64 total
  int s = i >> 6, j = i & 63;
  float invf = (float)pow(10000.0, -(double)j/64.0);
  float ang  = (float)s * invf;              // mimic fp32 reference rounding of the angle
  double a = (double)ang;
  tab[i] = make_float2((float)cos(a), (float)sin(a));
}

// ---------------- x fp32 -> bf16 ----------------
__global__ __launch_bounds__(256) void k_cvtx(const float* __restrict__ x, u16* __restrict__ xb){
  size_t i = (size_t)blockIdx.x*256 + threadIdx.x;   // each handles 8 elems; grid exact
  const float4v* xp = (const float4v*)x;
  float4v a = xp[i*2], c = xp[i*2+1];
  short8 o;
  o[0]=(short)f2bf(a[0]); o[1]=(short)f2bf(a[1]); o[2]=(short)f2bf(a[2]); o[3]=(short)f2bf(a[3]);
  o[4]=(short)f2bf(c[0]); o[5]=(short)f2bf(c[1]); o[6]=(short)f2bf(c[2]); o[7]=(short)f2bf(c[3]);
  *(short8*)(xb + i*8) = o;
}

// ---------------- weights fp32 -> bf16 (wq|wk|wv packed) ----------------
__global__ __launch_bounds__(256) void k_cvtw(const float* __restrict__ wq, const float* __restrict__ wk,
                                              const float* __restrict__ wv, u16* __restrict__ wb){
  int i = blockIdx.x*256 + threadIdx.x;      // 3*262144 total
  int m = i >> 18; int r = i & 262143;
  const float* s = (m==0) ? wq : ((m==1) ? wk : wv);
  wb[i] = f2bf(s[r]);
}

// ---------------- QKV projection GEMM + fused RoPE / V-transpose epilogue ----------------
// grid (128, 3): x-tile of 128 rows; y selects q/k/v. 4 waves, each 32 rows x 128 cols.
__global__ __launch_bounds__(256) void k_gemm(
    const u16* __restrict__ xb, const u16* __restrict__ wb, const float2* __restrict__ tab,
    u16* __restrict__ qb, u16* __restrict__ kb, u16* __restrict__ vt)
{
  __shared__ u16 lA[128*64];   // swizzled rows: byte = row*128 + (cb ^ ((row&7)<<4))
  __shared__ u16 lW[128*64];
  const int tid = threadIdx.x;
  const int wsel = blockIdx.y;
  const size_t M0 = (size_t)blockIdx.x * 128;
  const u16* Wm = wb + (size_t)wsel * (HD*DMODEL);
  const int w = tid >> 6, lane = tid & 63, lr = lane & 15, lg = lane >> 4;

  f32x4 acc[2][8];
  #pragma unroll
  for (int i=0;i<2;i++)
    #pragma unroll
    for (int j=0;j<8;j++) acc[i][j] = f32x4{0.f,0.f,0.f,0.f};

  const int Lb = tid*16;
  int srow[4], soff[4];
  #pragma unroll
  for (int i=0;i<4;i++){
    int L = i*4096 + Lb;
    int row = L >> 7, cb = L & 127;
    int scb = cb ^ ((row & 7) << 4);
    srow[i] = row; soff[i] = scb >> 1;
  }

  for (int k0 = 0; k0 < DMODEL; k0 += 64){
    #pragma unroll
    for (int i=0;i<4;i++){
      gload16(xb + (M0 + srow[i])*DMODEL + k0 + soff[i], ((char*)lA) + i*4096 + Lb);
      gload16(Wm + (size_t)srow[i]*DMODEL + k0 + soff[i], ((char*)lW) + i*4096 + Lb);
    }
    __syncthreads();
    short8 afr[2][2], bfr[8][2];
    #pragma unroll
    for (int rf=0; rf<2; rf++)
      #pragma unroll
      for (int ks=0; ks<2; ks++){
        int r = w*32 + rf*16 + lr;
        int byte = r*128 + ((ks*64 + lg*16) ^ ((r&7)<<4));
        afr[rf][ks] = *(const short8*)((const char*)lA + byte);
      }
    #pragma unroll
    for (int nf=0; nf<8; nf++)
      #pragma unroll
      for (int ks=0; ks<2; ks++){
        int r = nf*16 + lr;
        int byte = r*128 + ((ks*64 + lg*16) ^ ((r&7)<<4));
        bfr[nf][ks] = *(const short8*)((const char*)lW + byte);
      }
    #pragma unroll
    for (int rf=0; rf<2; rf++)
      #pragma unroll
      for (int nf=0; nf<8; nf++){
        acc[rf][nf] = __builtin_amdgcn_mfma_f32_16x16x32_bf16(afr[rf][0], bfr[nf][0], acc[rf][nf], 0,0,0);
        acc[rf][nf] = __builtin_amdgcn_mfma_f32_16x16x32_bf16(afr[rf][1], bfr[nf][1], acc[rf][nf], 0,0,0);
      }
    __syncthreads();
  }

  if (wsel < 2){
    u16* dst = (wsel == 0) ? qb : kb;
    #pragma unroll
    for (int rf=0; rf<2; rf++){
      #pragma unroll
      for (int reg=0; reg<4; reg++){
        size_t grow = M0 + w*32 + rf*16 + lg*4 + reg;
        int spos = (int)(grow & (SEQ-1));
        #pragma unroll
        for (int cf=0; cf<4; cf++){
          int j = cf*16 + lr;                 // 0..63
          float2 cs = tab[spos*64 + j];
          float lo = acc[rf][cf][reg];
          float hi = acc[rf][cf+4][reg];
          dst[grow*HD + j]      = f2bf(lo*cs.x - hi*cs.y);
          dst[grow*HD + j + 64] = f2bf(hi*cs.x + lo*cs.y);
        }
      }
    }
  } else {
    #pragma unroll
    for (int rf=0; rf<2; rf++)
      #pragma unroll
      for (int reg=0; reg<4; reg++){
        size_t grow = M0 + w*32 + rf*16 + lg*4 + reg;
        size_t b = grow >> 12;
        size_t spos = grow & (SEQ-1);
        #pragma unroll
        for (int cf=0; cf<8; cf++){
          int col = cf*16 + lr;
          vt[(b*HD + col)*SEQ + spos] = f2bf(acc[rf][cf][reg]);
        }
      }
  }
}

// ---------------- causal flash attention ----------------
// grid 256: block = (batch, q-tile of 64). 4 waves x 16 q-rows. KV tiles of 64.
__global__ __launch_bounds__(256) void k_attn(
    const u16* __restrict__ qb, const u16* __restrict__ kb, const u16* __restrict__ vt,
    float* __restrict__ out)
{
  __shared__ u16 lK[64*128];    // byte = kv*256 + (cb ^ ((kv&7)<<4))
  __shared__ u16 lV[128*64];    // byte = d*128  + (cb ^ ((d&7)<<4))
  __shared__ u16 lP[4][16*64];  // per-wave, byte = r*128 + (cb ^ ((r&7)<<4))
  const int tid = threadIdx.x;
  const int b  = blockIdx.x >> 6;
  const int qt = blockIdx.x & 63;
  const int w = tid >> 6, lane = tid & 63, lr = lane & 15, lg = lane >> 4;

  const size_t qrow = (size_t)b*SEQ + qt*64 + w*16 + lr;
  short8 aq[4];
  #pragma unroll
  for (int ks=0; ks<4; ks++)
    aq[ks] = *(const short8*)(qb + qrow*HD + ks*32 + lg*8);

  f32x4 accO[8];
  #pragma unroll
  for (int i=0;i<8;i++) accO[i] = f32x4{0.f,0.f,0.f,0.f};
  float m2[4]  = {-1e30f,-1e30f,-1e30f,-1e30f};
  float lsum[4] = {0.f,0.f,0.f,0.f};

  const int Lb = tid*16;
  const float cfac = SCALE * LOG2E;

  for (int kt = 0; kt <= qt; kt++){
    #pragma unroll
    for (int i=0;i<4;i++){
      int L = i*4096 + Lb;
      { int row = L >> 8, cb = L & 255;
        int scb = cb ^ ((row & 7) << 4);
        gload16(kb + ((size_t)b*SEQ + kt*64 + row)*HD + (scb>>1), ((char*)lK) + L); }
      { int row = L >> 7, cb = L & 127;
        int scb = cb ^ ((row & 7) << 4);
        gload16(vt + ((size_t)b*HD + row)*SEQ + kt*64 + (scb>>1), ((char*)lV) + L); }
    }
    __syncthreads();

    // S = Q K^T  (16 q-rows x 64 kv) in log2-domain units
    f32x4 sc[4];
    #pragma unroll
    for (int nf=0; nf<4; nf++){
      sc[nf] = f32x4{0.f,0.f,0.f,0.f};
      #pragma unroll
      for (int ks=0; ks<4; ks++){
        int r = nf*16 + lr;
        int byte = r*256 + ((ks*64 + lg*16) ^ ((r&7)<<4));
        short8 bk = *(const short8*)((const char*)lK + byte);
        sc[nf] = __builtin_amdgcn_mfma_f32_16x16x32_bf16(aq[ks], bk, sc[nf], 0,0,0);
      }
      sc[nf] *= cfac;
    }
    if (kt == qt){
      #pragma unroll
      for (int nf=0; nf<4; nf++)
        #pragma unroll
        for (int reg=0; reg<4; reg++){
          int col = nf*16 + lr;
          int row = w*16 + lg*4 + reg;
          if (col > row) sc[nf][reg] = -1e30f;
        }
    }
    float al[4];
    #pragma unroll
    for (int reg=0; reg<4; reg++){
      float v = fmaxf(fmaxf(sc[0][reg], sc[1][reg]), fmaxf(sc[2][reg], sc[3][reg]));
      v = fmaxf(v, __shfl_xor(v, 1));
      v = fmaxf(v, __shfl_xor(v, 2));
      v = fmaxf(v, __shfl_xor(v, 4));
      v = fmaxf(v, __shfl_xor(v, 8));
      float mnew = fmaxf(m2[reg], v);
      al[reg] = exp2f(m2[reg] - mnew);
      m2[reg] = mnew;
    }
    float prs[4] = {0.f,0.f,0.f,0.f};
    #pragma unroll
    for (int nf=0; nf<4; nf++)
      #pragma unroll
      for (int reg=0; reg<4; reg++){
        float p = exp2f(sc[nf][reg] - m2[reg]);
        prs[reg] += p;
        int r = lg*4 + reg;
        int byte = r*128 + ((nf*32 + lr*2) ^ ((r&7)<<4));
        *(u16*)(((char*)lP[w]) + byte) = f2bf(p);
      }
    f32x4 alv = f32x4{al[0], al[1], al[2], al[3]};
    #pragma unroll
    for (int reg=0; reg<4; reg++){
      float v = prs[reg];
      v += __shfl_xor(v, 1);
      v += __shfl_xor(v, 2);
      v += __shfl_xor(v, 4);
      v += __shfl_xor(v, 8);
      lsum[reg] = lsum[reg]*al[reg] + v;
    }
    #pragma unroll
    for (int cf=0; cf<8; cf++) accO[cf] *= alv;

    short8 pa[2];
    #pragma unroll
    for (int ks=0; ks<2; ks++){
      int byte = lr*128 + ((ks*64 + lg*16) ^ ((lr&7)<<4));
      pa[ks] = *(const short8*)(((const char*)lP[w]) + byte);
    }
    #pragma unroll
    for (int cf=0; cf<8; cf++){
      #pragma unroll
      for (int ks=0; ks<2; ks++){
        int d = cf*16 + lr;
        int byte = d*128 + ((ks*64 + lg*16) ^ ((d&7)<<4));
        short8 bv = *(const short8*)(((const char*)lV) + byte);
        accO[cf] = __builtin_amdgcn_mfma_f32_16x16x32_bf16(pa[ks], bv, accO[cf], 0,0,0);
      }
    }
    __syncthreads();
  }

  #pragma unroll
  for (int reg=0; reg<4; reg++){
    float inv = 1.0f / lsum[reg];
    size_t orow = (size_t)b*SEQ + qt*64 + w*16 + lg*4 + reg;
    #pragma unroll
    for (int cf=0; cf<8; cf++)
      out[orow*HD + cf*16 + lr] = accO[cf][reg] * inv;
  }
}

extern "C" void kernel_launch(void* const* d_in, const int* in_sizes, int n_in,
                              void* d_out, int out_size, void* d_ws, size_t ws_size,
                              hipStream_t stream){
  const float* x  = (const float*)d_in[0];
  const float* wq = (const float*)d_in[1];
  const float* wk = (const float*)d_in[2];
  const float* wv = (const float*)d_in[3];
  float* out = (float*)d_out;
  char* ws = (char*)d_ws;

  size_t off = 0;
  u16* xb = (u16*)(ws + off); off += (size_t)BS*DMODEL*2;     // 64 MB
  u16* wb = (u16*)(ws + off); off += (size_t)3*HD*DMODEL*2;   // 1.5 MB
  float2* tab = (float2*)(ws + off); off += (size_t)SEQ*64*8; // 2 MB
  u16* qb = (u16*)(ws + off); off += (size_t)BS*HD*2;         // 4 MB
  u16* kb = (u16*)(ws + off); off += (size_t)BS*HD*2;         // 4 MB
  u16* vt = (u16*)(ws + off); off += (size_t)BS*HD*2;         // 4 MB
  if (ws_size < off) return;  // insufficient workspace -> fail visibly

  hipLaunchKernelGGL(k_tab,  dim3(1024),  dim3(256), 0, stream, tab);
  hipLaunchKernelGGL(k_cvtx, dim3(16384), dim3(256), 0, stream, x, xb);
  hipLaunchKernelGGL(k_cvtw, dim3(3072),  dim3(256), 0, stream, wq, wk, wv, wb);
  hipLaunchKernelGGL(k_gemm, dim3(128,3), dim3(256), 0, stream, xb, wb, tab, qb, kb, vt);
  hipLaunchKernelGGL(k_attn, dim3(256),   dim3(256), 0, stream, qb, kb, vt, out);
}